// Round 1
// baseline (183.474 us; speedup 1.0000x reference)
//
#include <hip/hip_runtime.h>

#define LBL 32
#define NPIX (736 * 736)   // 541696
#define NQ (NPIX / 4)      // 135424 float4-quads per batch
#define QPB 512            // quads per block (2 per thread)
#define NBA 265            // ceil(NQ/QPB); block 264: only first quad-set valid
#define BATCH 8
#define DELTA_AGG 0.5f
#define DELTA_DIS 1.5f
#define REG_W 0.001f

// ws layout (float indices), ~6.2 MB — all slots plain-stored before read:
//  lab:   [0, +BATCH*NQ)               packed mask-only labels, 4 px per uint32
//  partA: [PA_BASE, +BATCH*NBA*192)    block-major: cnt_k[32]([0]=flag), sum[128], cnt_a[32]
//  red:   [RED_BASE, +BATCH*256)       per batch RAW totals, same elem order
//  partC: [PC_BASE, +BATCH*NBA*32)     block-major: val[32]
// NOTE: bf16 emb spill removed — emb (69 MB) is L3-resident (256 MB LLC), kC
// re-reads the f32 original instead. Saves ~35 MB write + ~35 MB read per iter.
#define LAB_BASE 0
#define PA_BASE (BATCH * NQ)                    // 1083392
#define RED_BASE (PA_BASE + BATCH * NBA * 192)  // 1490432
#define PC_BASE (RED_BASE + BATCH * 256)        // 1492480
// end: PC_BASE + 8*265*32 = 1560320 floats = 6.24 MB

// ===== Pass A: histograms (cnt_k, sums, cnt_a) + packed-label spill =========
// Counts use 5-bit ballot match-any: per j-slot, lanes group by label; only the
// lowest lane of each group does ONE conflict-free ds_add with popcount.
// This removes the 64-lane->32-bin same-address DS-atomic serialization that
// dominated kA (invisible in SQ_LDS_BANK_CONFLICT, which doesn't count
// atomic-RMW serialization). Component sums stay per-lane (sparse, ~15 active
// lanes over 124 addresses -> near conflict-free already).
__device__ __forceinline__ unsigned int procQuad(
    const int4 iv, const float4 kv, const float4 mv,
    const float4 e0, const float4 e1, const float4 e2, const float4 e3,
    const int lane, float* __restrict__ s_cnt, float* __restrict__ s_sum,
    float* __restrict__ s_cta, bool& has0) {
  const int labs[4] = {iv.x, iv.y, iv.z, iv.w};
  const float ks[4] = {kv.x, kv.y, kv.z, kv.w};
  const float ms[4] = {mv.x, mv.y, mv.z, mv.w};
  const float c0[4] = {e0.x, e0.y, e0.z, e0.w};
  const float c1[4] = {e1.x, e1.y, e1.z, e1.w};
  const float c2[4] = {e2.x, e2.y, e2.z, e2.w};
  const float c3[4] = {e3.x, e3.y, e3.z, e3.w};
  unsigned int labw = 0;
#pragma unroll
  for (int j = 0; j < 4; j++) {
    const bool m = ms[j] > 0.5f;
    const int li = m ? labs[j] : 0;
    const bool kf = m && (ks[j] > 0.5f);
    labw |= ((unsigned int)li) << (8 * j);
    const bool act = li > 0;
    // wave-uniform control flow here: ballots see all 64 lanes
    unsigned long long grp = __ballot(act);
    const unsigned long long kbal = __ballot(act && kf);
#pragma unroll
    for (int bb = 0; bb < 5; bb++) {
      const unsigned long long bal = __ballot((li >> bb) & 1);
      grp &= ((li >> bb) & 1) ? bal : ~bal;
    }
    if (act) {
      if ((int)__builtin_ctzll(grp) == lane)
        atomicAdd(&s_cta[li], (float)__popcll(grp));
      if (kf) {
        const unsigned long long gk = grp & kbal;
        if ((int)__builtin_ctzll(gk) == lane)
          atomicAdd(&s_cnt[li], (float)__popcll(gk));
        atomicAdd(&s_sum[li * 4 + 0], c0[j]);
        atomicAdd(&s_sum[li * 4 + 1], c1[j]);
        atomicAdd(&s_sum[li * 4 + 2], c2[j]);
        atomicAdd(&s_sum[li * 4 + 3], c3[j]);
      } else {
        has0 = true;
      }
    } else {
      has0 = true;
    }
  }
  return labw;
}

__global__ __launch_bounds__(256) void kA(
    const float* __restrict__ emb, const int* __restrict__ inst,
    const float* __restrict__ kern, const float* __restrict__ mask,
    float* __restrict__ ws) {
  const int b = blockIdx.y;
  const int t = threadIdx.x;
  const int lane = t & 63;
  __shared__ float s_cnt[LBL];   // [0] = "saw label 0" flag
  __shared__ float s_sum[LBL * 4];
  __shared__ float s_cta[LBL];   // mask-only counts (cnt_a)
  if (t < LBL) { s_cnt[t] = 0.f; s_cta[t] = 0.f; }
  if (t < LBL * 4) s_sum[t] = 0.f;
  __syncthreads();

  const long base = (long)b * NPIX;
  const float* ebase = emb + (long)b * 4 * NPIX;
  const int4* ip = (const int4*)(inst + base);
  const float4* kp = (const float4*)(kern + base);
  const float4* mp = (const float4*)(mask + base);
  const float4* p0 = (const float4*)(ebase);
  const float4* p1 = (const float4*)(ebase + NPIX);
  const float4* p2 = (const float4*)(ebase + 2 * NPIX);
  const float4* p3 = (const float4*)(ebase + 3 * NPIX);

  const int q0 = blockIdx.x * QPB + t;
  const int q1 = q0 + 256;
  const bool v1 = (q1 < NQ);  // block-uniform (false only for block 264)

  // issue loads up front — max MLP
  const int4 iva = ip[q0];
  const float4 kva = kp[q0], mva = mp[q0];
  const float4 ea0 = p0[q0], ea1 = p1[q0], ea2 = p2[q0], ea3 = p3[q0];
  int4 ivb;
  float4 kvb, mvb, fb0, fb1, fb2, fb3;
  if (v1) {
    ivb = ip[q1]; kvb = kp[q1]; mvb = mp[q1];
    fb0 = p0[q1]; fb1 = p1[q1]; fb2 = p2[q1]; fb3 = p3[q1];
  }

  bool has0 = false;
  unsigned int* labp = (unsigned int*)(ws + LAB_BASE) + (size_t)b * NQ;

  labp[q0] = procQuad(iva, kva, mva, ea0, ea1, ea2, ea3, lane,
                      s_cnt, s_sum, s_cta, has0);
  if (v1) {  // block-uniform -> ballots inside stay wave-complete
    labp[q1] = procQuad(ivb, kvb, mvb, fb0, fb1, fb2, fb3, lane,
                        s_cnt, s_sum, s_cta, has0);
  }

  if (has0) s_cnt[0] = 1.0f;  // benign race
  __syncthreads();
  // block-major coalesced partial store (no write amplification)
  float* po = ws + PA_BASE + ((size_t)b * NBA + blockIdx.x) * 192;
  if (t < 192)
    po[t] = (t < 32) ? s_cnt[t] : (t < 160 ? s_sum[t - 32] : s_cta[t - 160]);
}

// ===== Reduce A: one wave per (batch,elem) column, strided gather ===========
__global__ __launch_bounds__(256) void kB(float* __restrict__ ws) {
  const int b = blockIdx.y;
  const int col = blockIdx.x * 4 + (threadIdx.x >> 6);  // 48 blk x 4 waves = 192
  const int lane = threadIdx.x & 63;
  const float* pa = ws + PA_BASE + (size_t)b * NBA * 192 + col;
  float s = 0.f;
  for (int g = lane; g < NBA; g += 64) s += pa[(size_t)g * 192];
#pragma unroll
  for (int o = 32; o > 0; o >>= 1) s += __shfl_down(s, o);
  if (lane == 0) ws[RED_BASE + b * 256 + col] = s;  // raw totals
}

// ===== Pass C: aggregation val sums — re-reads f32 emb (L3-resident) ========
__device__ __forceinline__ void aggQuad(const unsigned int lw,
    const float4 e0, const float4 e1, const float4 e2, const float4 e3,
    const float* __restrict__ s_mean, float* __restrict__ s_val) {
  const float c0[4] = {e0.x, e0.y, e0.z, e0.w};
  const float c1[4] = {e1.x, e1.y, e1.z, e1.w};
  const float c2[4] = {e2.x, e2.y, e2.z, e2.w};
  const float c3[4] = {e3.x, e3.y, e3.z, e3.w};
#pragma unroll
  for (int j = 0; j < 4; j++) {
    const int li = (lw >> (8 * j)) & 0xFF;
    if (li > 0) {
      const float d0 = c0[j] - s_mean[li * 4 + 0];
      const float d1 = c1[j] - s_mean[li * 4 + 1];
      const float d2 = c2[j] - s_mean[li * 4 + 2];
      const float d3 = c3[j] - s_mean[li * 4 + 3];
      const float sq = d0 * d0 + d1 * d1 + d2 * d2 + d3 * d3;
      const float dist = (sq > 0.f) ? sqrtf(sq) : 0.f;
      const float tt = fmaxf(dist - DELTA_AGG, 0.f);
      atomicAdd(&s_val[li], logf(fmaf(tt, tt, 1.0f)));
    }
  }
}

__global__ __launch_bounds__(256) void kC(const float* __restrict__ emb,
                                          float* __restrict__ ws) {
  const int b = blockIdx.y;
  const int t = threadIdx.x;
  __shared__ float s_mean[LBL * 4];
  __shared__ float s_val[LBL];
  const float* rd = ws + RED_BASE + b * 256;
  if (t < LBL * 4) {
    const int l = t >> 2;
    s_mean[t] = (l == 0) ? 0.f : rd[32 + t] / fmaxf(rd[l], 1.0f);
  }
  if (t < LBL) s_val[t] = 0.f;
  __syncthreads();

  const unsigned int* labp = (const unsigned int*)(ws + LAB_BASE) + (size_t)b * NQ;
  const float* ebase = emb + (long)b * 4 * NPIX;
  const float4* p0 = (const float4*)(ebase);
  const float4* p1 = (const float4*)(ebase + NPIX);
  const float4* p2 = (const float4*)(ebase + 2 * NPIX);
  const float4* p3 = (const float4*)(ebase + 3 * NPIX);
  const int q0 = blockIdx.x * QPB + t;
  const int q1 = q0 + 256;
  const bool v1 = (q1 < NQ);

  const unsigned int lwa = labp[q0];
  const float4 ea0 = p0[q0], ea1 = p1[q0], ea2 = p2[q0], ea3 = p3[q0];
  unsigned int lwb = 0;
  float4 fb0, fb1, fb2, fb3;
  if (v1) {
    lwb = labp[q1];
    fb0 = p0[q1]; fb1 = p1[q1]; fb2 = p2[q1]; fb3 = p3[q1];
  }

  aggQuad(lwa, ea0, ea1, ea2, ea3, s_mean, s_val);
  if (v1) aggQuad(lwb, fb0, fb1, fb2, fb3, s_mean, s_val);

  __syncthreads();
  float* po = ws + PC_BASE + ((size_t)b * NBA + blockIdx.x) * 32;
  if (t < 32) po[t] = s_val[t];
}

// ===== Reduce C + finalize (one 1024-thread block per batch) ================
__global__ __launch_bounds__(1024) void kD(const float* __restrict__ ws,
                                           float* __restrict__ out) {
  const int b = blockIdx.x;
  const int t = threadIdx.x;
  const int col = t >> 5, sub = t & 31;  // 32 cols x 32 chunks
  const float* pc = ws + PC_BASE + (size_t)b * NBA * 32 + col;
  float s = 0.f;
  for (int g = sub; g < NBA; g += 32) s += pc[(size_t)g * 32];
  __shared__ float red[LBL][33];
  red[col][sub] = s;

  const float* rd = ws + RED_BASE + b * 256;
  __shared__ float sm[LBL * 4];
  __shared__ float scc[LBL];  // cnt_k
  __shared__ float sca[LBL];  // cnt_a
  if (t >= 512 && t < 640) {
    const int e = t - 512, l = e >> 2;
    sm[e] = (l == 0) ? 0.f : rd[32 + e] / fmaxf(rd[l], 1.0f);
  } else if (t >= 640 && t < 672) {
    scc[t - 640] = rd[t - 640];
  } else if (t >= 672 && t < 704) {
    sca[t - 672] = rd[160 + (t - 672)];
  }
  __syncthreads();
  __shared__ float sv[LBL];
  if (t < 32) {
    float v = 0.f;
#pragma unroll
    for (int k = 0; k < 32; k++) v += red[t][k];
    sv[t] = v;
  }
  __syncthreads();

  if (t < 64) {  // wave 0 only
    const int lane = t;
    const bool pres = (lane < LBL) && (scc[lane & 31] > 0.f);
    const unsigned long long bal_p = __ballot(pres);
    const int num_instance = __popcll(bal_p);
    const bool nz = pres && (lane > 0);
    const unsigned long long bal_nz = __ballot(nz);

    float agg = 0.f;
    if (nz) agg = sv[lane] / fmaxf(sca[lane], 1.0f);

    float reg = 0.f;
    if (pres) {
      float sq = 0.f;
#pragma unroll
      for (int d = 0; d < 4; d++) sq += sm[lane * 4 + d] * sm[lane * 4 + d];
      const float nrm = (sq > 0.f) ? sqrtf(sq) : 0.f;
      reg = logf(nrm + 1.0f);
    }

    float dis = 0.f, npair = 0.f;
    for (int pi = lane; pi < LBL * LBL; pi += 64) {
      const int i = pi >> 5, j = pi & 31;
      if (i != j && ((bal_nz >> i) & 1ull) && ((bal_nz >> j) & 1ull)) {
        float sq = 0.f;
#pragma unroll
        for (int d = 0; d < 4; d++) {
          const float df = sm[i * 4 + d] - sm[j * 4 + d];
          sq += df * df;
        }
        const float pdist = (sq > 0.f) ? sqrtf(sq) : 0.f;
        const float tt = fmaxf(2.0f * DELTA_DIS - pdist, 0.f);
        dis += logf(fmaf(tt, tt, 1.0f));
        npair += 1.0f;
      }
    }

#pragma unroll
    for (int o = 32; o > 0; o >>= 1) {
      agg += __shfl_down(agg, o);
      reg += __shfl_down(reg, o);
      dis += __shfl_down(dis, o);
      npair += __shfl_down(npair, o);
    }

    if (lane == 0) {
      const float l_agg = agg / fmaxf((float)(num_instance - 1), 1.0f);
      const float l_dis = (num_instance > 2) ? dis / fmaxf(npair, 1.0f) : 0.f;
      const float l_reg = reg / fmaxf((float)num_instance, 1.0f) * REG_W;
      const float loss = l_agg + l_dis + l_reg;
      out[b] = (num_instance <= 1) ? 0.f : loss;
    }
  }
}

extern "C" void kernel_launch(void* const* d_in, const int* in_sizes, int n_in,
                              void* d_out, int out_size, void* d_ws,
                              size_t ws_size, hipStream_t stream) {
  const float* emb = (const float*)d_in[0];
  const int* instance = (const int*)d_in[1];
  const float* kern = (const float*)d_in[2];
  const float* mask = (const float*)d_in[3];
  float* out = (float*)d_out;
  float* ws = (float*)d_ws;

  dim3 gridA(NBA, BATCH);  // 2120 blocks, 2 quads per thread
  kA<<<gridA, 256, 0, stream>>>(emb, instance, kern, mask, ws);
  dim3 gridB(48, BATCH);   // one wave per (batch, elem) column
  kB<<<gridB, 256, 0, stream>>>(ws);
  kC<<<gridA, 256, 0, stream>>>(emb, ws);
  kD<<<BATCH, 1024, 0, stream>>>(ws, out);
}